// Round 5
// baseline (156.819 us; speedup 1.0000x reference)
//
#include <hip/hip_runtime.h>

// SPD loss: 18-bin (9 class x 2 group) histogram over 16.7M int32 pairs + tiny epilogue.
// R0: scattered LDS atomics -> 55 us.
// R1: register-packed histogram -> same 55 us (warm==cold).
// R2: no global atomics -> 45 us, still warm==cold @ ~2.8 TB/s read.
// R3: 16-deep per-thread MLP burst -> no change. NOT latency/MLP-bound at the
//     software level; per-CU read rate pinned at ~4.5 B/cy (~ copy-bench read rate).
//     Hypothesis: L1/TCP miss-tracking depth limits outstanding lines per CU.
// R4: non-temporal (nt) streaming loads + 2-deep software pipeline (steady issue,
//     4 stages/block) to get past the L1 allocation path.

#define N_CLASSES 9
#define N_GROUPS 2
#define NBINS (N_CLASSES * N_GROUPS)  // 18
#define ITEMS 4                       // int4-pairs per thread per stage (16 elems < 127 field cap)
#define BLOCK 256

typedef int v4i __attribute__((ext_vector_type(4)));

__device__ __forceinline__ void acc_item(int pv, int av,
                                         unsigned long long& acc0,
                                         unsigned long long& acc1) {
    unsigned long long inc = 1ull << (7 * pv);
    acc0 += (av == 0) ? inc : 0ull;
    acc1 += (av == 0) ? 0ull : inc;
}

__global__ __launch_bounds__(BLOCK) void spd_hist_kernel(
    const int* __restrict__ preds,
    const int* __restrict__ attrs,
    unsigned int* __restrict__ partials,  // [gridDim.x][NBINS]
    int n4, int n)
{
    __shared__ unsigned int lh0[N_CLASSES];
    __shared__ unsigned int lh1[N_CLASSES];
    if (threadIdx.x < N_CLASSES) { lh0[threadIdx.x] = 0u; lh1[threadIdx.x] = 0u; }
    __syncthreads();

    unsigned int cnt[N_CLASSES];
    #pragma unroll
    for (int p = 0; p < N_CLASSES; ++p) cnt[p] = 0u;

    const v4i* __restrict__ p4 = (const v4i*)preds;
    const v4i* __restrict__ a4 = (const v4i*)attrs;
    const int tid = (int)threadIdx.x;

    const int span = BLOCK * ITEMS;            // int4s per block-stage
    const int stride = gridDim.x * span;

    v4i pb[2][ITEMS], ab[2][ITEMS];

    int S = blockIdx.x * span;
    int buf = 0;
    bool have = (S + span <= n4);

    if (have) {
        const int s = S + tid;
        #pragma unroll
        for (int k = 0; k < ITEMS; ++k) pb[0][k] = __builtin_nontemporal_load(p4 + s + k * BLOCK);
        #pragma unroll
        for (int k = 0; k < ITEMS; ++k) ab[0][k] = __builtin_nontemporal_load(a4 + s + k * BLOCK);
    }

    while (have) {
        const int Snext = S + stride;
        const bool havenext = (Snext + span <= n4);
        if (havenext) {
            const int s = Snext + tid;
            #pragma unroll
            for (int k = 0; k < ITEMS; ++k) pb[buf ^ 1][k] = __builtin_nontemporal_load(p4 + s + k * BLOCK);
            #pragma unroll
            for (int k = 0; k < ITEMS; ++k) ab[buf ^ 1][k] = __builtin_nontemporal_load(a4 + s + k * BLOCK);
        }

        // consume current stage: 7-bit field register histogram (<=16 per field)
        unsigned long long acc0 = 0ull, acc1 = 0ull;
        #pragma unroll
        for (int k = 0; k < ITEMS; ++k) {
            acc_item(pb[buf][k].x, ab[buf][k].x, acc0, acc1);
            acc_item(pb[buf][k].y, ab[buf][k].y, acc0, acc1);
            acc_item(pb[buf][k].z, ab[buf][k].z, acc0, acc1);
            acc_item(pb[buf][k].w, ab[buf][k].w, acc0, acc1);
        }
        #pragma unroll
        for (int p = 0; p < N_CLASSES; ++p) {
            cnt[p] += ((unsigned int)(acc0 >> (7 * p)) & 127u)
                    | (((unsigned int)(acc1 >> (7 * p)) & 127u) << 16);
        }

        buf ^= 1;
        S = Snext;
        have = havenext;
    }

    // at most one partial stage per block: S < n4 but S + span > n4
    if (S < n4) {
        unsigned long long acc0 = 0ull, acc1 = 0ull;
        for (int k = 0; k < ITEMS; ++k) {
            const int idx = S + tid + k * BLOCK;
            if (idx < n4) {
                v4i pp = p4[idx];
                v4i aa = a4[idx];
                acc_item(pp.x, aa.x, acc0, acc1);
                acc_item(pp.y, aa.y, acc0, acc1);
                acc_item(pp.z, aa.z, acc0, acc1);
                acc_item(pp.w, aa.w, acc0, acc1);
            }
        }
        #pragma unroll
        for (int p = 0; p < N_CLASSES; ++p) {
            cnt[p] += ((unsigned int)(acc0 >> (7 * p)) & 127u)
                    | (((unsigned int)(acc1 >> (7 * p)) & 127u) << 16);
        }
    }

    // scalar remainder (n % 4), block 0 only: <=3 items
    if (blockIdx.x == 0) {
        for (int t = n4 * 4 + tid; t < n; t += BLOCK)
            cnt[preds[t]] += (attrs[t] == 0) ? 1u : 0x10000u;
    }

    // wave-64 butterfly; 16-bit halves <= 64 * items/thread << 65536
    #pragma unroll
    for (int m = 1; m < 64; m <<= 1) {
        #pragma unroll
        for (int p = 0; p < N_CLASSES; ++p)
            cnt[p] += __shfl_xor(cnt[p], m, 64);
    }

    if ((tid & 63) == 0) {
        #pragma unroll
        for (int p = 0; p < N_CLASSES; ++p) {
            atomicAdd(&lh0[p], cnt[p] & 0xFFFFu);
            atomicAdd(&lh1[p], cnt[p] >> 16);
        }
    }
    __syncthreads();

    if (tid < NBINS) {
        int c = tid >> 1;
        unsigned int v = (tid & 1) ? lh1[c] : lh0[c];
        partials[blockIdx.x * NBINS + tid] = v;
    }
}

__global__ __launch_bounds__(1024) void spd_finalize_kernel(
    const unsigned int* __restrict__ partials,
    float* __restrict__ out, int nblocks, double n_total)
{
    __shared__ double counts[NBINS];
    const int tid = threadIdx.x;

    if (tid < NBINS * 32) {
        const int bin = tid >> 5;
        const int j = tid & 31;
        unsigned int s = 0u;
        #pragma unroll 8
        for (int b = j; b < nblocks; b += 32)
            s += partials[b * NBINS + bin];
        #pragma unroll
        for (int m = 1; m < 32; m <<= 1)
            s += __shfl_xor(s, m, 32);
        if (j == 0) counts[bin] = (double)s;
    }
    __syncthreads();

    if (tid == 0) {
        double n1 = 0.0;
        #pragma unroll
        for (int c = 0; c < N_CLASSES; ++c)
            n1 += counts[c * N_GROUPS + 1];
        double n0 = n_total - n1;
        double acc = 0.0;
        #pragma unroll
        for (int c = 0; c < N_CLASSES; ++c) {
            double d = counts[c * N_GROUPS] / n0 - counts[c * N_GROUPS + 1] / n1;
            acc += d * d;
        }
        out[0] = (float)acc;
    }
}

extern "C" void kernel_launch(void* const* d_in, const int* in_sizes, int n_in,
                              void* d_out, int out_size, void* d_ws, size_t ws_size,
                              hipStream_t stream)
{
    const int* preds = (const int*)d_in[0];
    const int* attrs = (const int*)d_in[1];
    const int n = in_sizes[0];

    unsigned int* partials = (unsigned int*)d_ws;

    const int n4 = n / 4;
    const int span = BLOCK * ITEMS;                 // 1024 int4 per block-stage
    int grid = (n4 + span - 1) / span;
    if (grid > 1024) grid = 1024;                   // -> 4 pipelined stages per block at N=16.7M
    int max_grid = (int)(ws_size / (NBINS * sizeof(unsigned int)));
    if (grid > max_grid) grid = max_grid;
    if (grid < 1) grid = 1;

    spd_hist_kernel<<<grid, BLOCK, 0, stream>>>(preds, attrs, partials, n4, n);
    spd_finalize_kernel<<<1, 1024, 0, stream>>>(partials, (float*)d_out, grid, (double)n);
}